// Round 4
// baseline (911.817 us; speedup 1.0000x reference)
//
#include <hip/hip_runtime.h>

typedef _Float16 half8   __attribute__((ext_vector_type(8)));
typedef _Float16 half4_t __attribute__((ext_vector_type(4)));
typedef float    float4_t __attribute__((ext_vector_type(4)));

#define B_   8
#define N_   4096
#define C_   256
#define F_   64

static __device__ __forceinline__ float4_t mfma16(half8 a, half8 b, float4_t c) {
  return __builtin_amdgcn_mfma_f32_16x16x32_f16(a, b, c, 0, 0, 0);
}

// ---------------- merged prep: transpose_x + weight prep in one launch ----------
// blocks [0,8192):       xT[b][c][n] = (f16)x[b][n][c]
// blocks [8192,8448):    whvt[d][c] = sum_e Wh[c][e]*Wv[e][d]
// blocks [8448,8576):    wfgt[n][c] = (n<64 ? Wf[c][n] : Wg[c][n-64])
__global__ __launch_bounds__(256) void prep_all(const float* __restrict__ x,
                                                const float* __restrict__ Wh,
                                                const float* __restrict__ Wv,
                                                const float* __restrict__ Wf,
                                                const float* __restrict__ Wg,
                                                _Float16* __restrict__ xT,
                                                _Float16* __restrict__ whvt,
                                                _Float16* __restrict__ wfgt) {
  __shared__ float tile[32][33];
  int blk = blockIdx.x;
  int tid = threadIdx.x;
  if (blk < 8192) {
    int b  = (blk & 1023) >> 7;
    int n0 = (blk & 127) << 5;
    int c0 = (blk >> 10) << 5;
    int r  = tid >> 3;
    int cc = (tid & 7) << 2;
    const float* src = x + ((size_t)(b * N_ + n0 + r)) * C_ + c0 + cc;
    float4_t v = *(const float4_t*)src;
    tile[r][cc + 0] = v[0]; tile[r][cc + 1] = v[1];
    tile[r][cc + 2] = v[2]; tile[r][cc + 3] = v[3];
    __syncthreads();
    half4_t o;
    o[0] = (_Float16)tile[cc + 0][r];
    o[1] = (_Float16)tile[cc + 1][r];
    o[2] = (_Float16)tile[cc + 2][r];
    o[3] = (_Float16)tile[cc + 3][r];
    _Float16* dst = xT + ((size_t)(b * C_ + c0 + r)) * N_ + n0 + cc;
    *(half4_t*)dst = o;
  } else if (blk < 8448) {
    int d = blk - 8192;
    int c = tid;
    const float4_t* whr = (const float4_t*)(Wh + (size_t)c * 256);
    float acc = 0.f;
#pragma unroll 8
    for (int e4 = 0; e4 < 64; ++e4) {
      float4_t w4 = whr[e4];
      acc += w4[0] * Wv[(e4 * 4 + 0) * 256 + d];
      acc += w4[1] * Wv[(e4 * 4 + 1) * 256 + d];
      acc += w4[2] * Wv[(e4 * 4 + 2) * 256 + d];
      acc += w4[3] * Wv[(e4 * 4 + 3) * 256 + d];
    }
    whvt[d * 256 + c] = (_Float16)acc;
  } else {
    int n = blk - 8448;
    int c = tid;
    float v = (n < 64) ? Wf[c * 64 + n] : Wg[c * 64 + (n - 64)];
    wfgt[n * 256 + c] = (_Float16)v;
  }
}

// ---------------- f,g GEMM: [32768x256] @ wfgt^T -> f16 [32768x64] x2 ------------
__global__ __launch_bounds__(256) void fg_kernel(const float* __restrict__ x,
                                                 const _Float16* __restrict__ wfgt,
                                                 _Float16* __restrict__ f,
                                                 _Float16* __restrict__ g) {
  int tid  = threadIdx.x;
  int wave = tid >> 6, lane = tid & 63;
  int n16  = lane & 15, quad = lane >> 4;
  int row  = blockIdx.x * 64 + wave * 16 + n16;
  float4_t acc[8];
#pragma unroll
  for (int t = 0; t < 8; t++) acc[t] = (float4_t){0.f, 0.f, 0.f, 0.f};
  for (int k0 = 0; k0 < 256; k0 += 32) {
    const float* xp = x + (size_t)row * C_ + k0 + quad * 8;
    float4_t x0 = *(const float4_t*)xp;
    float4_t x1 = *(const float4_t*)(xp + 4);
    half8 af;
#pragma unroll
    for (int j = 0; j < 4; j++) { af[j] = (_Float16)x0[j]; af[4 + j] = (_Float16)x1[j]; }
#pragma unroll
    for (int t = 0; t < 8; t++) {
      half8 bf = *(const half8*)(wfgt + (size_t)(t * 16 + n16) * 256 + k0 + quad * 8);
      acc[t] = mfma16(af, bf, acc[t]);
    }
  }
  int orow = blockIdx.x * 64 + wave * 16 + quad * 4;
#pragma unroll
  for (int t = 0; t < 8; t++) {
#pragma unroll
    for (int r = 0; r < 4; r++) {
      _Float16 v = (_Float16)acc[t][r];
      int col = t * 16 + n16;
      if (t < 4) f[(size_t)(orow + r) * 64 + col] = v;
      else       g[(size_t)(orow + r) * 64 + col - 64] = v;
    }
  }
}

// ---------------- flash attention, grid j-split ----------------------------------
// Grid (B, N/64, jsplit); 256 threads (4 waves). Block handles 64 Q-rows and the
// j-range [z*N/jsplit, (z+1)*N/jsplit). Wave w: S/softmax rows [16w,16w+16),
// PV channels [64w,64w+64) (C-split). Double-buffered swizzled K/P LDS tiles;
// V from L2-resident xT. Row-sum l computed by MFMA ones-column riding the
// alpha rescale. Partial output a_z = O/l_z (f16) + (m,l) per row to global;
// out_kernel merges. 33 KB LDS + ~104 VGPR -> 4 blocks/CU (16 waves/CU).
__global__ __launch_bounds__(256, 4) void flash_kernel(const _Float16* __restrict__ f,
                                                       const _Float16* __restrict__ g,
                                                       const _Float16* __restrict__ xT,
                                                       _Float16* __restrict__ a1,
                                                       _Float16* __restrict__ a2,
                                                       float2* __restrict__ mlb) {
  __shared__ _Float16 ktb2[2][64 * 64];
  __shared__ _Float16 ptb2[2][64 * 64];
  __shared__ float alpha_lds[2][64];
  __shared__ float l_lds[64];
  __shared__ int   skipf[2][4];

  const int b   = blockIdx.x;
  const int i0  = blockIdx.y * 64;
  const int jh  = blockIdx.z;
  const int iters = (N_ / 64) / gridDim.z;
  const int jbase = jh * (N_ / gridDim.z);
  const int tid = threadIdx.x;
  const int wave = tid >> 6, lane = tid & 63;
  const int n16 = lane & 15, quad = lane >> 4;
  const int nlo = n16 & 7, nhi = n16 >> 3;

  // Q fragments (A-layout: m=n16, k=quad*8+j)
  half8 qf[2];
  {
    const _Float16* qp = f + (size_t)(b * N_ + i0 + wave * 16 + n16) * 64 + quad * 8;
    qf[0] = *(const half8*)qp;
    qf[1] = *(const half8*)(qp + 32);
  }
  // ones-column B fragment: B[n][k] = (n==0)
  half8 onesb;
  {
    _Float16 ov = (n16 == 0) ? (_Float16)1.f : (_Float16)0.f;
#pragma unroll
    for (int j = 0; j < 8; j++) onesb[j] = ov;
  }

  float4_t o_acc[16];
#pragma unroll
  for (int t = 0; t < 16; t++) o_acc[t] = (float4_t){0.f, 0.f, 0.f, 0.f};
  float4_t lacc = (float4_t){0.f, 0.f, 0.f, 0.f};
  float m_i[4] = {-1e30f, -1e30f, -1e30f, -1e30f};

  const _Float16* gbase = g + (size_t)(b * N_ + jbase) * 64;
  const _Float16* xbase = xT + ((size_t)b * C_ + 64 * wave) * (size_t)N_;

  const int krow = tid >> 2;
  const int kcb  = (tid & 3) << 1;
  const int krb  = krow & 7;

  // prestage K tile for k=0
  {
    const _Float16* ks = gbase + (size_t)krow * 64 + (kcb << 3);
    half8 k0v = *(const half8*)ks;
    half8 k1v = *(const half8*)(ks + 8);
    _Float16* kd = ktb2[0] + krow * 64;
    *(half8*)(kd + (((kcb    ) ^ krb) << 3)) = k0v;
    *(half8*)(kd + (((kcb + 1) ^ krb) << 3)) = k1v;
  }
  __syncthreads();

  for (int k = 0; k < iters; ++k) {
    const int buf = k & 1;
    const int j0  = jbase + (k << 6);
    const int kn  = (k + 1) & (iters - 1);

    // prefetch next K tile into regs
    half8 kp0, kp1;
    {
      const _Float16* ks = gbase + (size_t)((kn << 6) + krow) * 64 + (kcb << 3);
      kp0 = *(const half8*)ks;
      kp1 = *(const half8*)(ks + 8);
    }
    // V fragments straight from L2-resident xT
    half8 vfr[8];
#pragma unroll
    for (int s = 0; s < 2; s++)
#pragma unroll
      for (int ct = 0; ct < 4; ct++)
        vfr[s * 4 + ct] = *(const half8*)(xbase + (size_t)(16 * ct + n16) * N_ +
                                          j0 + 32 * s + 8 * quad);

    // S = Q K^T for this wave's 16 rows
    float4_t s_acc[4];
#pragma unroll
    for (int t = 0; t < 4; t++) s_acc[t] = (float4_t){0.f, 0.f, 0.f, 0.f};
    {
      const _Float16* ktb = ktb2[buf];
#pragma unroll
      for (int s = 0; s < 2; s++)
#pragma unroll
        for (int t = 0; t < 4; t++) {
          half8 bf = *(const half8*)(ktb + (16 * t + n16) * 64 +
                                     (((4 * s + quad) ^ nlo) << 3));
          s_acc[t] = mfma16(qf[s], bf, s_acc[t]);
        }
    }

    // online softmax max/alpha for this wave's rows
    float alpha_r[4];
#pragma unroll
    for (int r = 0; r < 4; r++) {
      float v = fmaxf(fmaxf(s_acc[0][r], s_acc[1][r]),
                      fmaxf(s_acc[2][r], s_acc[3][r]));
#pragma unroll
      for (int d = 1; d < 16; d <<= 1)
        v = fmaxf(v, __shfl_xor(v, d, 16));
      float mn = fmaxf(m_i[r], v);
      alpha_r[r] = __expf(m_i[r] - mn);
      m_i[r] = mn;
    }
    _Float16* pb = ptb2[buf];
#pragma unroll
    for (int r = 0; r < 4; r++) {
      float s0 = __expf(s_acc[0][r] - m_i[r]);
      float s1 = __expf(s_acc[1][r] - m_i[r]);
      float s2 = __expf(s_acc[2][r] - m_i[r]);
      float s3 = __expf(s_acc[3][r] - m_i[r]);
      const int row = wave * 16 + 4 * quad + r;
      const int rb  = row & 7;
      _Float16* pr = pb + row * 64 + nlo;
      pr[((nhi    ) ^ rb) << 3] = (_Float16)s0;
      pr[((nhi + 2) ^ rb) << 3] = (_Float16)s1;
      pr[((nhi + 4) ^ rb) << 3] = (_Float16)s2;
      pr[((nhi + 6) ^ rb) << 3] = (_Float16)s3;
    }
    if (n16 == 0) {
#pragma unroll
      for (int r = 0; r < 4; r++)
        alpha_lds[buf][wave * 16 + 4 * quad + r] = alpha_r[r];
    }
    int aok = (alpha_r[0] == 1.f) && (alpha_r[1] == 1.f) &&
              (alpha_r[2] == 1.f) && (alpha_r[3] == 1.f);
    int wall = __all(aok);
    if (lane == 0) skipf[buf][wave] = wall;

    // write prefetched K tile into other buffer
    {
      _Float16* kd = ktb2[buf ^ 1] + krow * 64;
      *(half8*)(kd + (((kcb    ) ^ krb) << 3)) = kp0;
      *(half8*)(kd + (((kcb + 1) ^ krb) << 3)) = kp1;
    }
    __syncthreads();

    // rescale O + l (skipped when every row of the block has alpha==1)
    int sk = skipf[buf][0] & skipf[buf][1] & skipf[buf][2] & skipf[buf][3];
    if (!sk) {
#pragma unroll
      for (int ti = 0; ti < 4; ti++) {
#pragma unroll
        for (int r = 0; r < 4; r++) {
          float al = alpha_lds[buf][ti * 16 + 4 * quad + r];
#pragma unroll
          for (int ct = 0; ct < 4; ct++) o_acc[ti * 4 + ct][r] *= al;
        }
      }
#pragma unroll
      for (int r = 0; r < 4; r++) lacc[r] *= alpha_r[r];
    }

    // O += P V ; l += P 1 (rows owned by this wave)
#pragma unroll
    for (int s = 0; s < 2; s++)
#pragma unroll
      for (int ti = 0; ti < 4; ti++) {
        half8 af = *(const half8*)(pb + (16 * ti + n16) * 64 +
                                   (((4 * s + quad) ^ nlo) << 3));
        if (ti == wave) lacc = mfma16(af, onesb, lacc);
#pragma unroll
        for (int ct = 0; ct < 4; ct++)
          o_acc[ti * 4 + ct] = mfma16(af, vfr[s * 4 + ct], o_acc[ti * 4 + ct]);
      }
  }

  // share l across waves; emit (m,l) for the rows this wave owns
  if (n16 == 0) {
#pragma unroll
    for (int r = 0; r < 4; r++) {
      int row = wave * 16 + 4 * quad + r;
      l_lds[row] = lacc[r];
      mlb[((size_t)(b * 2 + jh)) * N_ + i0 + row] = make_float2(m_i[r], lacc[r]);
    }
  }
  __syncthreads();

  _Float16* ap = jh ? a2 : a1;
#pragma unroll
  for (int ti = 0; ti < 4; ti++)
#pragma unroll
    for (int r = 0; r < 4; r++) {
      int row = ti * 16 + 4 * quad + r;
      float il = 1.f / l_lds[row];
      size_t orow = (size_t)(b * N_ + i0 + row) * C_;
#pragma unroll
      for (int ct = 0; ct < 4; ct++)
        ap[orow + 64 * wave + 16 * ct + n16] =
            (_Float16)(o_acc[ti * 4 + ct][r] * il);
    }
}

// ---------------- epilogue: merge partials + GEMM: out = gamma*(a@Whv) + x -------
__global__ __launch_bounds__(256) void out_kernel(const _Float16* __restrict__ a1,
                                                  const _Float16* __restrict__ a2,
                                                  const float2* __restrict__ mlb,
                                                  const _Float16* __restrict__ whvt,
                                                  const float* __restrict__ x,
                                                  const float* __restrict__ gamma,
                                                  float* __restrict__ out,
                                                  int jsplit) {
  int tid  = threadIdx.x;
  int wave = tid >> 6, lane = tid & 63;
  int n16  = lane & 15, quad = lane >> 4;
  int colh = blockIdx.y;
  int row  = blockIdx.x * 64 + wave * 16 + n16;   // A m-index (global row)

  _Float16 c1h = (_Float16)1.f, c2h = (_Float16)0.f;
  if (jsplit == 2) {
    int b = row >> 12, i = row & (N_ - 1);
    float2 ml1 = mlb[((size_t)(b * 2 + 0)) * N_ + i];
    float2 ml2 = mlb[((size_t)(b * 2 + 1)) * N_ + i];
    float mm = fmaxf(ml1.x, ml2.x);
    float u1 = __expf(ml1.x - mm) * ml1.y;
    float u2 = __expf(ml2.x - mm) * ml2.y;
    float dn = u1 + u2;
    c1h = (_Float16)(u1 / dn);
    c2h = (_Float16)(u2 / dn);
  }

  float4_t acc[8];
#pragma unroll
  for (int t = 0; t < 8; t++) acc[t] = (float4_t){0.f, 0.f, 0.f, 0.f};
  for (int k0 = 0; k0 < 256; k0 += 32) {
    half8 af;
    if (jsplit == 2) {
      half8 v1 = *(const half8*)(a1 + (size_t)row * C_ + k0 + quad * 8);
      half8 v2 = *(const half8*)(a2 + (size_t)row * C_ + k0 + quad * 8);
      af = v1 * c1h + v2 * c2h;
    } else {
      af = *(const half8*)(a1 + (size_t)row * C_ + k0 + quad * 8);
    }
#pragma unroll
    for (int t = 0; t < 8; t++) {
      half8 bf = *(const half8*)(whvt + (size_t)(colh * 128 + t * 16 + n16) * 256 +
                                 k0 + quad * 8);
      acc[t] = mfma16(af, bf, acc[t]);
    }
  }
  float gm = gamma[0];
  int orow = blockIdx.x * 64 + wave * 16 + quad * 4;
#pragma unroll
  for (int t = 0; t < 8; t++) {
#pragma unroll
    for (int r = 0; r < 4; r++) {
      size_t idx = (size_t)(orow + r) * C_ + colh * 128 + t * 16 + n16;
      out[idx] = gm * acc[t][r] + x[idx];
    }
  }
}

extern "C" void kernel_launch(void* const* d_in, const int* in_sizes, int n_in,
                              void* d_out, int out_size, void* d_ws, size_t ws_size,
                              hipStream_t stream) {
  const float* x     = (const float*)d_in[0];
  const float* Wf    = (const float*)d_in[1];
  const float* Wg    = (const float*)d_in[2];
  const float* Wh    = (const float*)d_in[3];
  const float* Wv    = (const float*)d_in[4];
  const float* gamma = (const float*)d_in[5];
  float* out = (float*)d_out;

  char* w = (char*)d_ws;
  const size_t MB = 1024 * 1024;
  _Float16* whvt = (_Float16*)(w);                         // 128 KiB
  _Float16* wfgt = (_Float16*)(w + 131072);                //  64 KiB
  _Float16* fb   = (_Float16*)(w + 196608);                //   4 MiB
  _Float16* gb   = (_Float16*)(w + 196608 + 4 * MB);       //   4 MiB
  _Float16* xT   = (_Float16*)(w + 196608 + 8 * MB);       //  16 MiB
  _Float16* a1   = (_Float16*)(w + 196608 + 24 * MB);      //  16 MiB
  _Float16* a2   = (_Float16*)(w + 196608 + 40 * MB);      //  16 MiB (jsplit=2)
  float2*   mlb  = (float2*)  (w + 196608 + 56 * MB);      // 512 KiB (jsplit=2)

  int jsplit = (ws_size >= (size_t)60 * MB) ? 2 : 1;

  hipLaunchKernelGGL(prep_all, dim3(8576), dim3(256), 0, stream,
                     x, Wh, Wv, Wf, Wg, xT, whvt, wfgt);
  hipLaunchKernelGGL(fg_kernel, dim3(512), dim3(256), 0, stream, x, wfgt, fb, gb);
  hipLaunchKernelGGL(flash_kernel, dim3(8, 64, jsplit), dim3(256), 0, stream,
                     fb, gb, xT, a1, a2, mlb);
  hipLaunchKernelGGL(out_kernel, dim3(512, 2), dim3(256), 0, stream,
                     a1, a2, mlb, whvt, x, gamma, out, jsplit);
}

// Round 5
// 330.614 us; speedup vs baseline: 2.7580x; 2.7580x over previous
//
#include <hip/hip_runtime.h>

typedef _Float16 half8   __attribute__((ext_vector_type(8)));
typedef _Float16 half4_t __attribute__((ext_vector_type(4)));
typedef float    float4_t __attribute__((ext_vector_type(4)));

#define B_   8
#define N_   4096
#define C_   256
#define F_   64

static __device__ __forceinline__ float4_t mfma16(half8 a, half8 b, float4_t c) {
  return __builtin_amdgcn_mfma_f32_16x16x32_f16(a, b, c, 0, 0, 0);
}

// max-reduce across the 16 lanes of a DPP row (n16 groups) — pure VALU, no LDS.
static __device__ __forceinline__ float dpp_max16(float v) {
  int y;
  y = __builtin_amdgcn_update_dpp(0, __float_as_int(v), 0xB1, 0xF, 0xF, true);  // quad_perm xor1
  v = fmaxf(v, __int_as_float(y));
  y = __builtin_amdgcn_update_dpp(0, __float_as_int(v), 0x4E, 0xF, 0xF, true);  // quad_perm xor2
  v = fmaxf(v, __int_as_float(y));
  y = __builtin_amdgcn_update_dpp(0, __float_as_int(v), 0x124, 0xF, 0xF, true); // row_ror:4
  v = fmaxf(v, __int_as_float(y));
  y = __builtin_amdgcn_update_dpp(0, __float_as_int(v), 0x128, 0xF, 0xF, true); // row_ror:8
  v = fmaxf(v, __int_as_float(y));
  return v;
}

// ---------------- merged prep: transpose_x + weight prep -------------------------
__global__ __launch_bounds__(256) void prep_all(const float* __restrict__ x,
                                                const float* __restrict__ Wh,
                                                const float* __restrict__ Wv,
                                                const float* __restrict__ Wf,
                                                const float* __restrict__ Wg,
                                                _Float16* __restrict__ xT,
                                                _Float16* __restrict__ whvt,
                                                _Float16* __restrict__ wfgt) {
  __shared__ float tile[32][33];
  __shared__ float wvcol[256];
  int blk = blockIdx.x;
  int tid = threadIdx.x;
  if (blk < 8192) {
    int b  = (blk & 1023) >> 7;
    int n0 = (blk & 127) << 5;
    int c0 = (blk >> 10) << 5;
    int r  = tid >> 3;
    int cc = (tid & 7) << 2;
    const float* src = x + ((size_t)(b * N_ + n0 + r)) * C_ + c0 + cc;
    float4_t v = *(const float4_t*)src;
    tile[r][cc + 0] = v[0]; tile[r][cc + 1] = v[1];
    tile[r][cc + 2] = v[2]; tile[r][cc + 3] = v[3];
    __syncthreads();
    half4_t o;
    o[0] = (_Float16)tile[cc + 0][r];
    o[1] = (_Float16)tile[cc + 1][r];
    o[2] = (_Float16)tile[cc + 2][r];
    o[3] = (_Float16)tile[cc + 3][r];
    _Float16* dst = xT + ((size_t)(b * C_ + c0 + r)) * N_ + n0 + cc;
    *(half4_t*)dst = o;
  } else if (blk < 8448) {
    int d = blk - 8192;
    int c = tid;
    wvcol[c] = Wv[(size_t)c * 256 + d];   // one scattered load per thread, then LDS
    __syncthreads();
    const float4_t* whr = (const float4_t*)(Wh + (size_t)c * 256);
    float acc = 0.f;
#pragma unroll 8
    for (int e4 = 0; e4 < 64; ++e4) {
      float4_t w4 = whr[e4];
      acc += w4[0] * wvcol[e4 * 4 + 0];
      acc += w4[1] * wvcol[e4 * 4 + 1];
      acc += w4[2] * wvcol[e4 * 4 + 2];
      acc += w4[3] * wvcol[e4 * 4 + 3];
    }
    whvt[d * 256 + c] = (_Float16)acc;
  } else {
    int n = blk - 8448;
    int c = tid;
    float v = (n < 64) ? Wf[c * 64 + n] : Wg[c * 64 + (n - 64)];
    wfgt[n * 256 + c] = (_Float16)v;
  }
}

// ---------------- f,g GEMM: [32768x256] @ wfgt^T -> f16 [32768x64] x2 ------------
__global__ __launch_bounds__(256) void fg_kernel(const float* __restrict__ x,
                                                 const _Float16* __restrict__ wfgt,
                                                 _Float16* __restrict__ f,
                                                 _Float16* __restrict__ g) {
  int tid  = threadIdx.x;
  int wave = tid >> 6, lane = tid & 63;
  int n16  = lane & 15, quad = lane >> 4;
  int row  = blockIdx.x * 64 + wave * 16 + n16;
  float4_t acc[8];
#pragma unroll
  for (int t = 0; t < 8; t++) acc[t] = (float4_t){0.f, 0.f, 0.f, 0.f};
  for (int k0 = 0; k0 < 256; k0 += 32) {
    const float* xp = x + (size_t)row * C_ + k0 + quad * 8;
    float4_t x0 = *(const float4_t*)xp;
    float4_t x1 = *(const float4_t*)(xp + 4);
    half8 af;
#pragma unroll
    for (int j = 0; j < 4; j++) { af[j] = (_Float16)x0[j]; af[4 + j] = (_Float16)x1[j]; }
#pragma unroll
    for (int t = 0; t < 8; t++) {
      half8 bf = *(const half8*)(wfgt + (size_t)(t * 16 + n16) * 256 + k0 + quad * 8);
      acc[t] = mfma16(af, bf, acc[t]);
    }
  }
  int orow = blockIdx.x * 64 + wave * 16 + quad * 4;
#pragma unroll
  for (int t = 0; t < 8; t++) {
#pragma unroll
    for (int r = 0; r < 4; r++) {
      _Float16 v = (_Float16)acc[t][r];
      int col = t * 16 + n16;
      if (t < 4) f[(size_t)(orow + r) * 64 + col] = v;
      else       g[(size_t)(orow + r) * 64 + col - 64] = v;
    }
  }
}

// ---------------- flash attention, software-pipelined ----------------------------
// Round-2 skeleton (256 thr, C-split PV, double-buffered swizzled K/P LDS, V from
// L2-resident xT) with the PV+rescale of tile k-1 deferred into iteration k so its
// 34 MFMAs issue underneath softmax(k)'s VALU. l via MFMA-ones column; row-max via
// DPP (no LDS swizzles). 2 blocks/CU (reg-bound) — ILP, not TLP, hides the chain.
__global__ __launch_bounds__(256, 2) void flash_kernel(const _Float16* __restrict__ f,
                                                       const _Float16* __restrict__ g,
                                                       const _Float16* __restrict__ xT,
                                                       _Float16* __restrict__ a) {
  __shared__ _Float16 ktb2[2][64 * 64];
  __shared__ _Float16 ptb2[2][64 * 64];
  __shared__ float alpha_lds[2][64];
  __shared__ float l_lds[64];
  __shared__ int   skipf[2][4];

  const int b   = blockIdx.x;
  const int i0  = blockIdx.y * 64;
  const int tid = threadIdx.x;
  const int wave = tid >> 6, lane = tid & 63;
  const int n16 = lane & 15, quad = lane >> 4;
  const int nlo = n16 & 7, nhi = n16 >> 3;

  half8 qf[2];
  {
    const _Float16* qp = f + (size_t)(b * N_ + i0 + wave * 16 + n16) * 64 + quad * 8;
    qf[0] = *(const half8*)qp;
    qf[1] = *(const half8*)(qp + 32);
  }
  half8 onesb;
  {
    _Float16 ov = (n16 == 0) ? (_Float16)1.f : (_Float16)0.f;
#pragma unroll
    for (int j = 0; j < 8; j++) onesb[j] = ov;
  }

  float4_t o_acc[16];
#pragma unroll
  for (int t = 0; t < 16; t++) o_acc[t] = (float4_t){0.f, 0.f, 0.f, 0.f};
  float4_t lacc = (float4_t){0.f, 0.f, 0.f, 0.f};
  float m_i[4] = {-1e30f, -1e30f, -1e30f, -1e30f};
  float alpha_prev[4] = {1.f, 1.f, 1.f, 1.f};
  half8 vfr[8];

  const _Float16* gbase = g + (size_t)(b * N_) * 64;
  const _Float16* xbase = xT + ((size_t)b * C_ + 64 * wave) * (size_t)N_;

  const int krow = tid >> 2;
  const int kcb  = (tid & 3) << 1;
  const int krb  = krow & 7;

  // prestage K(0)
  {
    const _Float16* ks = gbase + (size_t)krow * 64 + (kcb << 3);
    half8 k0v = *(const half8*)ks;
    half8 k1v = *(const half8*)(ks + 8);
    _Float16* kd = ktb2[0] + krow * 64;
    *(half8*)(kd + (((kcb    ) ^ krb) << 3)) = k0v;
    *(half8*)(kd + (((kcb + 1) ^ krb) << 3)) = k1v;
  }
  __syncthreads();

  for (int k = 0; k < 64; ++k) {
    const int buf = k & 1;
    const int j0  = k << 6;
    const int kn  = (k + 1) & 63;

    // prefetch K(k+1) into regs
    half8 kp0, kp1;
    {
      const _Float16* ks = gbase + (size_t)((kn << 6) + krow) * 64 + (kcb << 3);
      kp0 = *(const half8*)ks;
      kp1 = *(const half8*)(ks + 8);
    }

    // S(k) — issue first so its results land while PV(k-1) issues
    float4_t s_acc[4];
#pragma unroll
    for (int t = 0; t < 4; t++) s_acc[t] = (float4_t){0.f, 0.f, 0.f, 0.f};
    {
      const _Float16* ktb = ktb2[buf];
#pragma unroll
      for (int s = 0; s < 2; s++)
#pragma unroll
        for (int t = 0; t < 4; t++) {
          half8 bf = *(const half8*)(ktb + (16 * t + n16) * 64 +
                                     (((4 * s + quad) ^ nlo) << 3));
          s_acc[t] = mfma16(qf[s], bf, s_acc[t]);
        }
    }

    // deferred PV(k-1): rescale by alpha(k-1), then O += P(k-1) V(k-1)
    if (k > 0) {
      const int pb_ = buf ^ 1;
      int sk = skipf[pb_][0] & skipf[pb_][1] & skipf[pb_][2] & skipf[pb_][3];
      if (!sk) {
#pragma unroll
        for (int ti = 0; ti < 4; ti++)
#pragma unroll
          for (int r = 0; r < 4; r++) {
            float al = alpha_lds[pb_][ti * 16 + 4 * quad + r];
#pragma unroll
            for (int ct = 0; ct < 4; ct++) o_acc[ti * 4 + ct][r] *= al;
          }
#pragma unroll
        for (int r = 0; r < 4; r++) lacc[r] *= alpha_prev[r];
      }
      const _Float16* pbm = ptb2[pb_];
#pragma unroll
      for (int s = 0; s < 2; s++)
#pragma unroll
        for (int ti = 0; ti < 4; ti++) {
          half8 af = *(const half8*)(pbm + (16 * ti + n16) * 64 +
                                     (((4 * s + quad) ^ nlo) << 3));
          if (ti == wave) lacc = mfma16(af, onesb, lacc);
#pragma unroll
          for (int ct = 0; ct < 4; ct++)
            o_acc[ti * 4 + ct] = mfma16(af, vfr[s * 4 + ct], o_acc[ti * 4 + ct]);
        }
    }

    // softmax(k): DPP row-max, exp, write P(k)
    float alpha_r[4];
#pragma unroll
    for (int r = 0; r < 4; r++) {
      float v = fmaxf(fmaxf(s_acc[0][r], s_acc[1][r]),
                      fmaxf(s_acc[2][r], s_acc[3][r]));
      v = dpp_max16(v);
      float mn = fmaxf(m_i[r], v);
      alpha_r[r] = __expf(m_i[r] - mn);
      m_i[r] = mn;
    }
    _Float16* pb = ptb2[buf];
#pragma unroll
    for (int r = 0; r < 4; r++) {
      float s0 = __expf(s_acc[0][r] - m_i[r]);
      float s1 = __expf(s_acc[1][r] - m_i[r]);
      float s2 = __expf(s_acc[2][r] - m_i[r]);
      float s3 = __expf(s_acc[3][r] - m_i[r]);
      const int row = wave * 16 + 4 * quad + r;
      const int rb  = row & 7;
      _Float16* pr = pb + row * 64 + nlo;
      pr[((nhi    ) ^ rb) << 3] = (_Float16)s0;
      pr[((nhi + 2) ^ rb) << 3] = (_Float16)s1;
      pr[((nhi + 4) ^ rb) << 3] = (_Float16)s2;
      pr[((nhi + 6) ^ rb) << 3] = (_Float16)s3;
    }
    if (n16 == 0) {
#pragma unroll
      for (int r = 0; r < 4; r++)
        alpha_lds[buf][wave * 16 + 4 * quad + r] = alpha_r[r];
    }
    {
      int aok = (alpha_r[0] == 1.f) && (alpha_r[1] == 1.f) &&
                (alpha_r[2] == 1.f) && (alpha_r[3] == 1.f);
      int wall = __all(aok);
      if (lane == 0) skipf[buf][wave] = wall;
    }
#pragma unroll
    for (int r = 0; r < 4; r++) alpha_prev[r] = alpha_r[r];

    // stage K(k+1)
    {
      _Float16* kd = ktb2[buf ^ 1] + krow * 64;
      *(half8*)(kd + (((kcb    ) ^ krb) << 3)) = kp0;
      *(half8*)(kd + (((kcb + 1) ^ krb) << 3)) = kp1;
    }
    // load V(k) for use at iter k+1
#pragma unroll
    for (int s = 0; s < 2; s++)
#pragma unroll
      for (int ct = 0; ct < 4; ct++)
        vfr[s * 4 + ct] = *(const half8*)(xbase + (size_t)(16 * ct + n16) * N_ +
                                          j0 + 32 * s + 8 * quad);
    __syncthreads();
  }

  // final deferred PV(63)
  {
    const int pb_ = 1;
    int sk = skipf[pb_][0] & skipf[pb_][1] & skipf[pb_][2] & skipf[pb_][3];
    if (!sk) {
#pragma unroll
      for (int ti = 0; ti < 4; ti++)
#pragma unroll
        for (int r = 0; r < 4; r++) {
          float al = alpha_lds[pb_][ti * 16 + 4 * quad + r];
#pragma unroll
          for (int ct = 0; ct < 4; ct++) o_acc[ti * 4 + ct][r] *= al;
        }
#pragma unroll
      for (int r = 0; r < 4; r++) lacc[r] *= alpha_prev[r];
    }
    const _Float16* pbm = ptb2[pb_];
#pragma unroll
    for (int s = 0; s < 2; s++)
#pragma unroll
      for (int ti = 0; ti < 4; ti++) {
        half8 af = *(const half8*)(pbm + (16 * ti + n16) * 64 +
                                   (((4 * s + quad) ^ nlo) << 3));
        if (ti == wave) lacc = mfma16(af, onesb, lacc);
#pragma unroll
        for (int ct = 0; ct < 4; ct++)
          o_acc[ti * 4 + ct] = mfma16(af, vfr[s * 4 + ct], o_acc[ti * 4 + ct]);
      }
  }

  // share l (ones-column lives in n16==0 lanes), then write a = O / l
  if (n16 == 0) {
#pragma unroll
    for (int r = 0; r < 4; r++)
      l_lds[wave * 16 + 4 * quad + r] = lacc[r];
  }
  __syncthreads();
#pragma unroll
  for (int ti = 0; ti < 4; ti++)
#pragma unroll
    for (int r = 0; r < 4; r++) {
      int row = ti * 16 + 4 * quad + r;
      float il = 1.f / l_lds[row];
      size_t orow = (size_t)(b * N_ + i0 + row) * C_;
#pragma unroll
      for (int ct = 0; ct < 4; ct++)
        a[orow + 64 * wave + 16 * ct + n16] =
            (_Float16)(o_acc[ti * 4 + ct][r] * il);
    }
}

// ---------------- epilogue GEMM: out = gamma * (a @ Whv) + x, col-split 2x -------
__global__ __launch_bounds__(256) void out_kernel(const _Float16* __restrict__ a,
                                                  const _Float16* __restrict__ whvt,
                                                  const float* __restrict__ x,
                                                  const float* __restrict__ gamma,
                                                  float* __restrict__ out) {
  int tid  = threadIdx.x;
  int wave = tid >> 6, lane = tid & 63;
  int n16  = lane & 15, quad = lane >> 4;
  int colh = blockIdx.y;
  int row  = blockIdx.x * 64 + wave * 16 + n16;
  float4_t acc[8];
#pragma unroll
  for (int t = 0; t < 8; t++) acc[t] = (float4_t){0.f, 0.f, 0.f, 0.f};
  for (int k0 = 0; k0 < 256; k0 += 32) {
    half8 af = *(const half8*)(a + (size_t)row * C_ + k0 + quad * 8);
#pragma unroll
    for (int t = 0; t < 8; t++) {
      half8 bf = *(const half8*)(whvt + (size_t)(colh * 128 + t * 16 + n16) * 256 +
                                 k0 + quad * 8);
      acc[t] = mfma16(af, bf, acc[t]);
    }
  }
  float gm = gamma[0];
  int orow = blockIdx.x * 64 + wave * 16 + quad * 4;
#pragma unroll
  for (int t = 0; t < 8; t++) {
#pragma unroll
    for (int r = 0; r < 4; r++) {
      size_t idx = (size_t)(orow + r) * C_ + colh * 128 + t * 16 + n16;
      out[idx] = gm * acc[t][r] + x[idx];
    }
  }
}

extern "C" void kernel_launch(void* const* d_in, const int* in_sizes, int n_in,
                              void* d_out, int out_size, void* d_ws, size_t ws_size,
                              hipStream_t stream) {
  const float* x     = (const float*)d_in[0];
  const float* Wf    = (const float*)d_in[1];
  const float* Wg    = (const float*)d_in[2];
  const float* Wh    = (const float*)d_in[3];
  const float* Wv    = (const float*)d_in[4];
  const float* gamma = (const float*)d_in[5];
  float* out = (float*)d_out;

  char* w = (char*)d_ws;
  const size_t MB = 1024 * 1024;
  _Float16* whvt = (_Float16*)(w);                         // 128 KiB
  _Float16* wfgt = (_Float16*)(w + 131072);                //  64 KiB
  _Float16* fb   = (_Float16*)(w + 196608);                //   4 MiB
  _Float16* gb   = (_Float16*)(w + 196608 + 4 * MB);       //   4 MiB
  _Float16* xT   = (_Float16*)(w + 196608 + 8 * MB);       //  16 MiB
  _Float16* ab   = (_Float16*)(w + 196608 + 24 * MB);      //  16 MiB

  hipLaunchKernelGGL(prep_all, dim3(8576), dim3(256), 0, stream,
                     x, Wh, Wv, Wf, Wg, xT, whvt, wfgt);
  hipLaunchKernelGGL(fg_kernel, dim3(512), dim3(256), 0, stream, x, wfgt, fb, gb);
  hipLaunchKernelGGL(flash_kernel, dim3(8, 64), dim3(256), 0, stream,
                     fb, gb, xT, ab);
  hipLaunchKernelGGL(out_kernel, dim3(512, 2), dim3(256), 0, stream,
                     ab, whvt, x, gamma, out);
}